// Round 1
// baseline (141.872 us; speedup 1.0000x reference)
//
#include <hip/hip_runtime.h>
#include <hip/hip_bf16.h>
#include <math.h>

#define H 512
#define B 64
#define L 4096

// ---------------------------------------------------------------------------
// Kernel 1: v[b,h] = sum_o hidden[b,o] * W[o,h];  c[b] = sum_o hidden[b,o]*bias[o]
// 64 blocks (one per b), 512 threads (one per h).
// ---------------------------------------------------------------------------
__global__ __launch_bounds__(512) void proj_kernel(
    const float* __restrict__ hidden,   // [B,H]
    const float* __restrict__ W,        // [H,H]  (o-major: W[o*H+h])
    const float* __restrict__ bias,     // [H]
    float* __restrict__ v,              // [B,H]
    float* __restrict__ c)              // [B]
{
    const int b = blockIdx.x;
    const int h = threadIdx.x;

    __shared__ float hsh[H];
    hsh[h] = hidden[b * H + h];
    __syncthreads();

    float acc = 0.f;
#pragma unroll 8
    for (int o = 0; o < H; ++o) {
        acc = fmaf(hsh[o], W[o * H + h], acc);
    }
    v[b * H + h] = acc;

    // c[b] = dot(hidden[b,:], bias)
    float p = hsh[h] * bias[h];
#pragma unroll
    for (int off = 32; off; off >>= 1) p += __shfl_xor(p, off);

    __shared__ float red[8];
    if ((h & 63) == 0) red[h >> 6] = p;
    __syncthreads();
    if (h == 0) {
        float s = 0.f;
#pragma unroll
        for (int i = 0; i < 8; ++i) s += red[i];
        c[b] = s;
    }
}

// ---------------------------------------------------------------------------
// Kernel 2: energies[b,l] = enc[l,b,:] . v[b,:] + c[b]
// Block = 256 threads = 4 waves. Each block: one b, 64 consecutive l.
// Each wave: 16 rows; v-fragment kept in registers across rows.
// enc row (512 contiguous floats) read as 2x float4 per lane -> fully coalesced.
// ---------------------------------------------------------------------------
#define ROWS_PER_WAVE 16
#define ROWS_PER_BLOCK 64

__global__ __launch_bounds__(256) void energies_kernel(
    const float* __restrict__ enc,      // [L,B,H]
    const float* __restrict__ v,        // [B,H]
    const float* __restrict__ c,        // [B]
    float* __restrict__ energies)       // [B,L]
{
    const int wave = threadIdx.x >> 6;
    const int lane = threadIdx.x & 63;

    const int chunks_per_b = L / ROWS_PER_BLOCK;      // 64
    const int b     = blockIdx.x / chunks_per_b;
    const int chunk = blockIdx.x % chunks_per_b;
    const int l0    = chunk * ROWS_PER_BLOCK + wave * ROWS_PER_WAVE;

    // v fragment: lane holds float4 at positions lane and 64+lane of v[b,:]
    const float4* v4 = reinterpret_cast<const float4*>(v + (size_t)b * H);
    const float4 va = v4[lane];
    const float4 vb = v4[64 + lane];
    const float  cb = c[b];

#pragma unroll 4
    for (int i = 0; i < ROWS_PER_WAVE; ++i) {
        const int l = l0 + i;
        const float4* row =
            reinterpret_cast<const float4*>(enc + ((size_t)l * B + b) * H);
        const float4 ea = row[lane];
        const float4 eb = row[64 + lane];

        float s = ea.x * va.x + ea.y * va.y + ea.z * va.z + ea.w * va.w;
        s = fmaf(eb.x, vb.x, s);
        s = fmaf(eb.y, vb.y, s);
        s = fmaf(eb.z, vb.z, s);
        s = fmaf(eb.w, vb.w, s);

#pragma unroll
        for (int off = 32; off; off >>= 1) s += __shfl_xor(s, off);

        if (lane == 0) energies[(size_t)b * L + l] = s + cb;
    }
}

// ---------------------------------------------------------------------------
// Kernel 3: out[b,0,:] = softmax(energies[b,:])
// 64 blocks (one per b), 256 threads, 16 elements/thread in registers.
// ---------------------------------------------------------------------------
__global__ __launch_bounds__(256) void softmax_kernel(
    const float* __restrict__ energies, // [B,L]
    float* __restrict__ out)            // [B,1,L]
{
    const int b = blockIdx.x;
    const int t = threadIdx.x;
    const float* e = energies + (size_t)b * L;
    float* o = out + (size_t)b * L;

    float vals[16];
    float m = -1e30f;
#pragma unroll
    for (int i = 0; i < 16; ++i) {
        vals[i] = e[t + i * 256];
        m = fmaxf(m, vals[i]);
    }
#pragma unroll
    for (int off = 32; off; off >>= 1) m = fmaxf(m, __shfl_xor(m, off));

    __shared__ float redm[4];
    if ((t & 63) == 0) redm[t >> 6] = m;
    __syncthreads();
    m = fmaxf(fmaxf(redm[0], redm[1]), fmaxf(redm[2], redm[3]));

    float s = 0.f;
#pragma unroll
    for (int i = 0; i < 16; ++i) {
        vals[i] = expf(vals[i] - m);
        s += vals[i];
    }
#pragma unroll
    for (int off = 32; off; off >>= 1) s += __shfl_xor(s, off);

    __shared__ float reds[4];
    if ((t & 63) == 0) reds[t >> 6] = s;
    __syncthreads();
    s = reds[0] + reds[1] + reds[2] + reds[3];

    const float inv = 1.0f / s;
#pragma unroll
    for (int i = 0; i < 16; ++i) o[t + i * 256] = vals[i] * inv;
}

// ---------------------------------------------------------------------------
extern "C" void kernel_launch(void* const* d_in, const int* in_sizes, int n_in,
                              void* d_out, int out_size, void* d_ws, size_t ws_size,
                              hipStream_t stream)
{
    const float* hidden = (const float*)d_in[0];   // [1,B,H]
    const float* enc    = (const float*)d_in[1];   // [L,B,H]
    const float* W      = (const float*)d_in[2];   // [H,H]
    const float* bias   = (const float*)d_in[3];   // [H]
    float* out = (float*)d_out;                    // [B,1,L]

    float* v        = (float*)d_ws;                // B*H   = 32768 floats
    float* c        = v + (size_t)B * H;           // B     = 64 floats
    float* energies = c + B;                       // B*L   = 262144 floats

    proj_kernel<<<B, H, 0, stream>>>(hidden, W, bias, v, c);

    const int nblocks = B * (L / ROWS_PER_BLOCK);  // 4096
    energies_kernel<<<nblocks, 256, 0, stream>>>(enc, v, c, energies);

    softmax_kernel<<<B, 256, 0, stream>>>(energies, out);
}